// Round 3
// baseline (548.970 us; speedup 1.0000x reference)
//
#include <hip/hip_runtime.h>

#define BB 32768
#define BS (BB*16)   // 524288

// ---- ws float offsets ----
#define H0   0               // h0f[16] c0f[16] h0b[16] c0b[16]
#define RECO 64              // rec[16]
#define TAB  128             // disc F table, 8193 floats over [-8,8]
#define HFO  8448            // final h fwd, B*16 floats
#define HBO  (HFO+BS)        // final h bwd

__device__ __forceinline__ float sigm(float x){
    return __builtin_amdgcn_rcpf(1.f + __expf(-x));
}
__device__ __forceinline__ float tanh_f(float x){
    return 1.f - 2.f * __builtin_amdgcn_rcpf(1.f + __expf(2.f * x));
}

struct P29 { const float* p[29]; };
// 0 values 1 masks 2-4 g_fwd(Wih,Whh,b) 5-7 g_bwd 8 impW 9 impb
// 10 fcW 11 fcb 12-14 dec(Wih,Whh,b) 15 dec_out_W 16 dec_out_b 17 disc_out_W
// 18 disc_out_b 19/20 d_W_0/d_b_0 ... 27/28 d_W_4/d_b_4

// Full discriminator as scalar->scalar function (f gate dead: cc=sig(i)*tanh(g))
__device__ float disc_F(float xin, const P29& a)
{
    const float* W0 = a.p[19]; const float* B0 = a.p[20];
    float a0[32];
    #pragma unroll
    for (int u = 0; u < 32; u++) {
        float gi = xin * W0[u]      + B0[u];
        float gg = xin * W0[64 + u] + B0[64 + u];
        float go = xin * W0[96 + u] + B0[96 + u];
        a0[u] = sigm(go) * tanh_f(sigm(gi) * tanh_f(gg));
    }
    const float* W1 = a.p[21]; const float* B1 = a.p[22];
    float a1[16];
    #pragma unroll
    for (int u = 0; u < 16; u++) {
        float gi = B1[u], gg = B1[32 + u], go = B1[48 + u];
        #pragma unroll
        for (int k = 0; k < 32; k++) {
            gi += a0[k] * W1[u*32 + k];
            gg += a0[k] * W1[(32+u)*32 + k];
            go += a0[k] * W1[(48+u)*32 + k];
        }
        a1[u] = sigm(go) * tanh_f(sigm(gi) * tanh_f(gg));
    }
    const float* W2 = a.p[23]; const float* B2 = a.p[24];
    float a2[8];
    #pragma unroll
    for (int u = 0; u < 8; u++) {
        float gi = B2[u], gg = B2[16 + u], go = B2[24 + u];
        #pragma unroll
        for (int k = 0; k < 16; k++) {
            gi += a1[k] * W2[u*16 + k];
            gg += a1[k] * W2[(16+u)*16 + k];
            go += a1[k] * W2[(24+u)*16 + k];
        }
        a2[u] = sigm(go) * tanh_f(sigm(gi) * tanh_f(gg));
    }
    const float* W3 = a.p[25]; const float* B3 = a.p[26];
    float a3[16];
    #pragma unroll
    for (int u = 0; u < 16; u++) {
        float gi = B3[u], gg = B3[32 + u], go = B3[48 + u];
        #pragma unroll
        for (int k = 0; k < 8; k++) {
            gi += a2[k] * W3[u*8 + k];
            gg += a2[k] * W3[(32+u)*8 + k];
            go += a2[k] * W3[(48+u)*8 + k];
        }
        a3[u] = sigm(go) * tanh_f(sigm(gi) * tanh_f(gg));
    }
    const float* W4 = a.p[27]; const float* B4 = a.p[28];
    float a4[32];
    #pragma unroll
    for (int u = 0; u < 32; u++) {
        float gi = B4[u], gg = B4[64 + u], go = B4[96 + u];
        #pragma unroll
        for (int k = 0; k < 16; k++) {
            gi += a3[k] * W4[u*16 + k];
            gg += a3[k] * W4[(64+u)*16 + k];
            go += a3[k] * W4[(96+u)*16 + k];
        }
        a4[u] = sigm(go) * tanh_f(sigm(gi) * tanh_f(gg));
    }
    float dout = a.p[18][0];
    #pragma unroll
    for (int k = 0; k < 32; k++) dout += a4[k] * a.p[17][k];
    return dout;
}

// ---- prep: block0 = init states + batch-invariant decoder; blocks 1.. = F table ----
__global__ __launch_bounds__(256) void k_prep(P29 a, float* __restrict__ ws)
{
    int tid = threadIdx.x;
    if (blockIdx.x != 0) {
        int idx = (blockIdx.x - 1) * 256 + tid;
        if (idx < 8193)
            ws[TAB + idx] = disc_F(-8.f + (float)idx * (1.f/512.f), a);
        return;
    }
    // initial generator states: x = +/-128, h=c=0 (f gate * c=0 dead)
    if (tid < 32) {
        int dir = tid >> 4, u = tid & 15;
        const float* Wih = a.p[2 + 3*dir];
        const float* bia = a.p[4 + 3*dir];
        float s = dir ? -128.f : 128.f;
        float gi = s * Wih[u]      + bia[u];
        float gg = s * Wih[32 + u] + bia[32 + u];
        float go = s * Wih[48 + u] + bia[48 + u];
        float c0 = sigm(gi) * tanh_f(gg);
        ws[H0 + dir*32 + u]      = sigm(go) * tanh_f(c0);
        ws[H0 + dir*32 + 16 + u] = c0;
    }
    // decoder: batch-invariant -> compute once
    __shared__ float dh[16], dc[16];
    const float* Wih = a.p[12];
    const float* Whh = a.p[13];
    const float* bb  = a.p[14];
    const float* oW  = a.p[15];
    const float* ob  = a.p[16];
    if (tid < 16) {
        int u = tid;
        float gi = bb[u], gg = bb[32+u], go = bb[48+u];
        #pragma unroll
        for (int k = 0; k < 16; k++) {
            gi += 128.f * Wih[u*16 + k];
            gg += 128.f * Wih[(32+u)*16 + k];
            go += 128.f * Wih[(48+u)*16 + k];
        }
        float c0 = sigm(gi) * tanh_f(gg);
        dc[u] = c0; dh[u] = sigm(go) * tanh_f(c0);
    }
    __syncthreads();
    for (int t = 0; t < 16; t++) {
        float rx[16], rh[16], cold = 0.f;
        if (tid < 16) {
            #pragma unroll
            for (int k = 0; k < 16; k++) { rx[k] = dc[k]; rh[k] = dh[k]; }
            cold = dc[tid];
        }
        __syncthreads();
        if (tid < 16) {
            int u = tid;
            float gi = bb[u], gf = bb[16+u], gg = bb[32+u], go = bb[48+u];
            #pragma unroll
            for (int k = 0; k < 16; k++) {
                gi += rx[k]*Wih[u*16+k]      + rh[k]*Whh[u*16+k];
                gf += rx[k]*Wih[(16+u)*16+k] + rh[k]*Whh[(16+u)*16+k];
                gg += rx[k]*Wih[(32+u)*16+k] + rh[k]*Whh[(32+u)*16+k];
                go += rx[k]*Wih[(48+u)*16+k] + rh[k]*Whh[(48+u)*16+k];
            }
            float cn = sigm(gf)*cold + sigm(gi)*tanh_f(gg);
            dc[u] = cn; dh[u] = sigm(go)*tanh_f(cn);
        }
        __syncthreads();
        if (tid == 0) {
            float o = ob[0];
            #pragma unroll
            for (int k = 0; k < 16; k++) o += dh[k] * oW[k];
            ws[RECO + t] = o;
        }
        __syncthreads();
    }
}

// ---- generator LSTM scan: one thread per (b, dir), per-unit gate eval (no g[64]) ----
__global__ __launch_bounds__(256) void k_lstm(P29 a, const int* __restrict__ masks,
                                              float* __restrict__ ws)
{
    int dir = (int)(blockIdx.x >= (BB/256));
    int b = blockIdx.x * 256 + threadIdx.x - dir * BB;
    const float* __restrict__ Wih  = a.p[2 + 3*dir];   // [64]
    const float* __restrict__ Whh  = a.p[3 + 3*dir];   // [64][16]
    const float* __restrict__ bia  = a.p[4 + 3*dir];   // [64]
    const float* __restrict__ impW = a.p[8];           // [16]
    const float impb = a.p[9][0];
    float x[16]; unsigned mm = 0;
    {
        const float4* vp = (const float4*)(a.p[0] + (size_t)b*16);
        #pragma unroll
        for (int q = 0; q < 4; q++) {
            float4 v = vp[q];
            x[q*4+0]=v.x; x[q*4+1]=v.y; x[q*4+2]=v.z; x[q*4+3]=v.w;
        }
        const int4* mp = (const int4*)(masks + (size_t)b*16);
        #pragma unroll
        for (int q = 0; q < 4; q++) {
            int4 v = mp[q];
            mm |= (v.x!=0?1u:0u) << (q*4+0);
            mm |= (v.y!=0?1u:0u) << (q*4+1);
            mm |= (v.z!=0?1u:0u) << (q*4+2);
            mm |= (v.w!=0?1u:0u) << (q*4+3);
        }
    }
    float h[16], c[16];
    #pragma unroll
    for (int u = 0; u < 16; u++) {
        h[u] = ws[H0 + dir*32 + u];
        c[u] = ws[H0 + dir*32 + 16 + u];
    }
    for (int t = 0; t < 16; t++) {
        float imp = impb;
        #pragma unroll
        for (int k = 0; k < 16; k++) imp += h[k] * impW[k];
        float cc = ((mm >> t) & 1u) ? imp : x[t];
        float hn[16];
        #pragma unroll
        for (int u = 0; u < 16; u++) {
            float gi = cc * Wih[u]    + bia[u];
            float gf = cc * Wih[16+u] + bia[16+u];
            float gg = cc * Wih[32+u] + bia[32+u];
            float go = cc * Wih[48+u] + bia[48+u];
            #pragma unroll
            for (int k = 0; k < 16; k++) {
                gi += h[k] * Whh[u*16 + k];
                gf += h[k] * Whh[(16+u)*16 + k];
                gg += h[k] * Whh[(32+u)*16 + k];
                go += h[k] * Whh[(48+u)*16 + k];
            }
            float cn = sigm(gf) * c[u] + sigm(gi) * tanh_f(gg);
            c[u] = cn;
            hn[u] = sigm(go) * tanh_f(cn);
        }
        #pragma unroll
        for (int u = 0; u < 16; u++) h[u] = hn[u];
    }
    float* o = ws + HFO + (size_t)dir * BS + (size_t)b * 16;
    #pragma unroll
    for (int q = 0; q < 4; q++)
        ((float4*)o)[q] = make_float4(h[q*4], h[q*4+1], h[q*4+2], h[q*4+3]);
}

// ---- per (b,t): imputed, latent, reconstructed, disc via F-table lerp ----
__global__ __launch_bounds__(256) void k_post(P29 a, const int* __restrict__ masks,
                                              const float* __restrict__ ws,
                                              float* __restrict__ out)
{
    int e = blockIdx.x * 256 + threadIdx.x;   // 0..BS-1
    int b = e >> 4, t = e & 15;
    const float4* hf4 = (const float4*)(ws + HFO + (size_t)b*16);
    const float4* hb4 = (const float4*)(ws + HBO + (size_t)b*16);
    float hs[16];
    #pragma unroll
    for (int q = 0; q < 4; q++) {
        float4 f = hf4[q], g = hb4[q];
        hs[q*4+0]=f.x+g.x; hs[q*4+1]=f.y+g.y; hs[q*4+2]=f.z+g.z; hs[q*4+3]=f.w+g.w;
    }
    float x = a.p[0][e];
    int m = masks[e];
    float imputed = m ? x : hs[t];
    out[e] = imputed;
    // latent[b][t] = fc_b[t] + hs . fc_W[t,:]
    float lat = a.p[11][t];
    #pragma unroll
    for (int k = 0; k < 16; k++) lat += hs[k] * a.p[10][t*16 + k];
    out[2*BS + e] = lat;
    // reconstructed: batch-invariant broadcast
    out[3*BS + e] = ws[RECO + t];
    // disc: F-table linear interp
    float xx = fminf(fmaxf(imputed, -8.f), 8.f);
    float f = (xx + 8.f) * 512.f;                 // [0, 8192]
    float fi = floorf(f);
    int i = (int)fi; i = i > 8191 ? 8191 : i;
    float w = f - fi;
    float t0 = ws[TAB + i], t1 = ws[TAB + i + 1];
    out[BS + e] = fmaf(w, t1 - t0, t0);
}

extern "C" void kernel_launch(void* const* d_in, const int* in_sizes, int n_in,
                              void* d_out, int out_size, void* d_ws, size_t ws_size,
                              hipStream_t stream)
{
    float* ws = (float*)d_ws;
    P29 a;
    for (int i = 0; i < 29; i++) a.p[i] = (const float*)d_in[i];
    const int* masks = (const int*)d_in[1];
    k_prep<<<34, 256, 0, stream>>>(a, ws);                    // block0 prep + 33 table blocks
    k_lstm<<<(2*BB)/256, 256, 0, stream>>>(a, masks, ws);
    k_post<<<BS/256, 256, 0, stream>>>(a, masks, ws, (float*)d_out);
}

// Round 4
// 212.851 us; speedup vs baseline: 2.5791x; 2.5791x over previous
//
#include <hip/hip_runtime.h>

#define BB 32768
#define BS (BB*16)   // 524288

// ---- ws float offsets ----
#define H0   0               // h0f[16] c0f[16] h0b[16] c0b[16]
#define RECO 64              // rec[16]
#define TAB  128             // disc F table, 8193 floats over [-8,8]
#define HFO  8448            // final h fwd, B*16 floats
#define HBO  (HFO+BS)        // final h bwd

// ---- LDS layout for disc weights (table blocks) ----
#define LW0 0
#define LB0 128
#define LW1 256
#define LB1 2304
#define LW2 2368
#define LB2 2880
#define LW3 2912
#define LB3 3424
#define LW4 3488
#define LB4 5536
#define LOW 5664
#define LOB 5696
#define NDW 5697

__device__ __forceinline__ float sigm(float x){
    return __builtin_amdgcn_rcpf(1.f + __expf(-x));
}
__device__ __forceinline__ float tanh_f(float x){
    return 1.f - 2.f * __builtin_amdgcn_rcpf(1.f + __expf(2.f * x));
}

struct P29 { const float* p[29]; };
// 0 values 1 masks 2-4 g_fwd(Wih,Whh,b) 5-7 g_bwd 8 impW 9 impb
// 10 fcW 11 fcb 12-14 dec(Wih,Whh,b) 15 dec_out_W 16 dec_out_b 17 disc_out_W
// 18 disc_out_b 19/20 d_W_0/d_b_0 ... 27/28 d_W_4/d_b_4

// disc as scalar->scalar, weights from LDS (broadcast reads, no s_load chains)
__device__ float disc_F_lds(float xin, const float* __restrict__ w)
{
    float a0[32];
    #pragma unroll
    for (int u = 0; u < 32; u++) {
        float gi = xin * w[LW0 + u]      + w[LB0 + u];
        float gg = xin * w[LW0 + 64 + u] + w[LB0 + 64 + u];
        float go = xin * w[LW0 + 96 + u] + w[LB0 + 96 + u];
        a0[u] = sigm(go) * tanh_f(sigm(gi) * tanh_f(gg));
    }
    float a1[16];
    #pragma unroll
    for (int u = 0; u < 16; u++) {
        float gi = w[LB1 + u], gg = w[LB1 + 32 + u], go = w[LB1 + 48 + u];
        #pragma unroll
        for (int k = 0; k < 32; k++) {
            gi += a0[k] * w[LW1 + u*32 + k];
            gg += a0[k] * w[LW1 + (32+u)*32 + k];
            go += a0[k] * w[LW1 + (48+u)*32 + k];
        }
        a1[u] = sigm(go) * tanh_f(sigm(gi) * tanh_f(gg));
    }
    float a2[8];
    #pragma unroll
    for (int u = 0; u < 8; u++) {
        float gi = w[LB2 + u], gg = w[LB2 + 16 + u], go = w[LB2 + 24 + u];
        #pragma unroll
        for (int k = 0; k < 16; k++) {
            gi += a1[k] * w[LW2 + u*16 + k];
            gg += a1[k] * w[LW2 + (16+u)*16 + k];
            go += a1[k] * w[LW2 + (24+u)*16 + k];
        }
        a2[u] = sigm(go) * tanh_f(sigm(gi) * tanh_f(gg));
    }
    float a3[16];
    #pragma unroll
    for (int u = 0; u < 16; u++) {
        float gi = w[LB3 + u], gg = w[LB3 + 32 + u], go = w[LB3 + 48 + u];
        #pragma unroll
        for (int k = 0; k < 8; k++) {
            gi += a2[k] * w[LW3 + u*8 + k];
            gg += a2[k] * w[LW3 + (32+u)*8 + k];
            go += a2[k] * w[LW3 + (48+u)*8 + k];
        }
        a3[u] = sigm(go) * tanh_f(sigm(gi) * tanh_f(gg));
    }
    float a4[32];
    #pragma unroll
    for (int u = 0; u < 32; u++) {
        float gi = w[LB4 + u], gg = w[LB4 + 64 + u], go = w[LB4 + 96 + u];
        #pragma unroll
        for (int k = 0; k < 16; k++) {
            gi += a3[k] * w[LW4 + u*16 + k];
            gg += a3[k] * w[LW4 + (64+u)*16 + k];
            go += a3[k] * w[LW4 + (96+u)*16 + k];
        }
        a4[u] = sigm(go) * tanh_f(sigm(gi) * tanh_f(gg));
    }
    float dout = w[LOB];
    #pragma unroll
    for (int k = 0; k < 32; k++) dout += a4[k] * w[LOW + k];
    return dout;
}

// ---- prep: block0 = init states + decoder scan; blocks 1.. = F table (LDS-staged) ----
__global__ __launch_bounds__(256) void k_prep(P29 a, float* __restrict__ ws)
{
    __shared__ float wl[NDW];
    int tid = threadIdx.x;
    if (blockIdx.x != 0) {
        // cooperative coalesced load of all disc weights into LDS
        #define CP(SRC, DST, N) { const float* s = a.p[SRC]; \
            for (int i = tid; i < (N); i += 256) wl[(DST)+i] = s[i]; }
        CP(19, LW0, 128)  CP(20, LB0, 128)
        CP(21, LW1, 2048) CP(22, LB1, 64)
        CP(23, LW2, 512)  CP(24, LB2, 32)
        CP(25, LW3, 512)  CP(26, LB3, 64)
        CP(27, LW4, 2048) CP(28, LB4, 128)
        CP(17, LOW, 32)   CP(18, LOB, 1)
        #undef CP
        __syncthreads();
        int idx = (blockIdx.x - 1) * 256 + tid;
        if (idx < 8193)
            ws[TAB + idx] = disc_F_lds(-8.f + (float)idx * (1.f/512.f), wl);
        return;
    }
    // initial generator states: x = +/-128, h=c=0 (f gate * c=0 dead)
    if (tid < 32) {
        int dir = tid >> 4, u = tid & 15;
        const float* Wih = a.p[2 + 3*dir];
        const float* bia = a.p[4 + 3*dir];
        float s = dir ? -128.f : 128.f;
        float gi = s * Wih[u]      + bia[u];
        float gg = s * Wih[32 + u] + bia[32 + u];
        float go = s * Wih[48 + u] + bia[48 + u];
        float c0 = sigm(gi) * tanh_f(gg);
        ws[H0 + dir*32 + u]      = sigm(go) * tanh_f(c0);
        ws[H0 + dir*32 + 16 + u] = c0;
    }
    // decoder: batch-invariant, once; lane u holds its 4 gate rows in registers
    __shared__ float dh[16], dc[16];
    const float* Wih = a.p[12];
    const float* Whh = a.p[13];
    const float* bb  = a.p[14];
    const float* oW  = a.p[15];
    const float* ob  = a.p[16];
    float wii[16], wff[16], wgg[16], woo[16];
    float vii[16], vff[16], vgg[16], voo[16];
    float bi_r=0, bf_r=0, bg_r=0, bo_r=0;
    if (tid < 16) {
        int u = tid;
        #pragma unroll
        for (int k = 0; k < 16; k++) {
            wii[k]=Wih[u*16+k];      vii[k]=Whh[u*16+k];
            wff[k]=Wih[(16+u)*16+k]; vff[k]=Whh[(16+u)*16+k];
            wgg[k]=Wih[(32+u)*16+k]; vgg[k]=Whh[(32+u)*16+k];
            woo[k]=Wih[(48+u)*16+k]; voo[k]=Whh[(48+u)*16+k];
        }
        bi_r=bb[u]; bf_r=bb[16+u]; bg_r=bb[32+u]; bo_r=bb[48+u];
        float gi = bi_r, gg = bg_r, go = bo_r;
        #pragma unroll
        for (int k = 0; k < 16; k++) {
            gi += 128.f * wii[k];
            gg += 128.f * wgg[k];
            go += 128.f * woo[k];
        }
        float c0 = sigm(gi) * tanh_f(gg);
        dc[u] = c0; dh[u] = sigm(go) * tanh_f(c0);
    }
    __syncthreads();
    for (int t = 0; t < 16; t++) {
        float rx[16], rh[16], cold = 0.f;
        if (tid < 16) {
            #pragma unroll
            for (int k = 0; k < 16; k++) { rx[k] = dc[k]; rh[k] = dh[k]; }
            cold = dc[tid];
        }
        __syncthreads();
        if (tid < 16) {
            float gi = bi_r, gf = bf_r, gg = bg_r, go = bo_r;
            #pragma unroll
            for (int k = 0; k < 16; k++) {
                gi += rx[k]*wii[k] + rh[k]*vii[k];
                gf += rx[k]*wff[k] + rh[k]*vff[k];
                gg += rx[k]*wgg[k] + rh[k]*vgg[k];
                go += rx[k]*woo[k] + rh[k]*voo[k];
            }
            float cn = sigm(gf)*cold + sigm(gi)*tanh_f(gg);
            dc[tid] = cn; dh[tid] = sigm(go)*tanh_f(cn);
        }
        __syncthreads();
        if (tid == 0) {
            float o = ob[0];
            #pragma unroll
            for (int k = 0; k < 16; k++) o += dh[k] * oW[k];
            ws[RECO + t] = o;
        }
        __syncthreads();
    }
}

// ---- generator LSTM: 16 lanes per (b,dir); weights live in VGPRs, h via shfl ----
__global__ __launch_bounds__(256) void k_lstm(P29 a, const int* __restrict__ masks,
                                              float* __restrict__ ws)
{
    int T = blockIdx.x * 256 + threadIdx.x;      // 0 .. 2^20-1
    int dir = T >> 19;
    int idx = T & 0x7FFFF;
    int u = idx & 15;                             // hidden unit owned by this lane
    int b = idx >> 4;
    int lane = threadIdx.x & 63;
    int gbase = lane & 48;                        // first lane of this 16-lane group
    const float* __restrict__ Whh = a.p[3 + 3*dir];
    // per-lane hoisted weights: the 4 gate rows of unit u
    float wi[16], wf[16], wg[16], wo[16];
    #pragma unroll
    for (int q = 0; q < 4; q++) {
        float4 vi = ((const float4*)(Whh + (u)*16))[q];
        float4 vf = ((const float4*)(Whh + (16+u)*16))[q];
        float4 vg = ((const float4*)(Whh + (32+u)*16))[q];
        float4 vo = ((const float4*)(Whh + (48+u)*16))[q];
        wi[q*4+0]=vi.x; wi[q*4+1]=vi.y; wi[q*4+2]=vi.z; wi[q*4+3]=vi.w;
        wf[q*4+0]=vf.x; wf[q*4+1]=vf.y; wf[q*4+2]=vf.z; wf[q*4+3]=vf.w;
        wg[q*4+0]=vg.x; wg[q*4+1]=vg.y; wg[q*4+2]=vg.z; wg[q*4+3]=vg.w;
        wo[q*4+0]=vo.x; wo[q*4+1]=vo.y; wo[q*4+2]=vo.z; wo[q*4+3]=vo.w;
    }
    const float* __restrict__ Wih = a.p[2 + 3*dir];
    const float* __restrict__ bia = a.p[4 + 3*dir];
    float xi = Wih[u], xf = Wih[16+u], xg = Wih[32+u], xo = Wih[48+u];
    float bi = bia[u], bf = bia[16+u], bg = bia[32+u], bo = bia[48+u];
    float impw[16];
    #pragma unroll
    for (int q = 0; q < 4; q++) {
        float4 v = ((const float4*)a.p[8])[q];
        impw[q*4+0]=v.x; impw[q*4+1]=v.y; impw[q*4+2]=v.z; impw[q*4+3]=v.w;
    }
    float impb = a.p[9][0];
    // distributed inputs: lane u holds x[u], mask[u] of batch b (coalesced)
    float x_own = a.p[0][(size_t)b*16 + u];
    int   m_own = masks[(size_t)b*16 + u];
    float h = ws[H0 + dir*32 + u];
    float c = ws[H0 + dir*32 + 16 + u];
    for (int t = 0; t < 16; t++) {
        float hh[16];
        float imp = impb;
        #pragma unroll
        for (int k = 0; k < 16; k++) {
            hh[k] = __shfl(h, gbase + k);
            imp += hh[k] * impw[k];
        }
        float xt = __shfl(x_own, gbase + t);
        int   mt = __shfl(m_own, gbase + t);
        float cc = mt ? imp : xt;
        float gi = bi + cc*xi, gf = bf + cc*xf, gg = bg + cc*xg, go = bo + cc*xo;
        #pragma unroll
        for (int k = 0; k < 16; k++) {
            gi += hh[k]*wi[k];
            gf += hh[k]*wf[k];
            gg += hh[k]*wg[k];
            go += hh[k]*wo[k];
        }
        float cn = sigm(gf)*c + sigm(gi)*tanh_f(gg);
        c = cn;
        h = sigm(go)*tanh_f(cn);
    }
    ws[HFO + (size_t)dir*BS + (size_t)b*16 + u] = h;   // coalesced
}

// ---- per (b,t): imputed, latent, reconstructed, disc via F-table lerp ----
__global__ __launch_bounds__(256) void k_post(P29 a, const int* __restrict__ masks,
                                              const float* __restrict__ ws,
                                              float* __restrict__ out)
{
    int e = blockIdx.x * 256 + threadIdx.x;   // 0..BS-1
    int b = e >> 4, t = e & 15;
    const float4* hf4 = (const float4*)(ws + HFO + (size_t)b*16);
    const float4* hb4 = (const float4*)(ws + HBO + (size_t)b*16);
    float hs[16];
    #pragma unroll
    for (int q = 0; q < 4; q++) {
        float4 f = hf4[q], g = hb4[q];
        hs[q*4+0]=f.x+g.x; hs[q*4+1]=f.y+g.y; hs[q*4+2]=f.z+g.z; hs[q*4+3]=f.w+g.w;
    }
    float x = a.p[0][e];
    int m = masks[e];
    float imputed = m ? x : hs[t];
    out[e] = imputed;
    float lat = a.p[11][t];
    #pragma unroll
    for (int k = 0; k < 16; k++) lat += hs[k] * a.p[10][t*16 + k];
    out[2*BS + e] = lat;
    out[3*BS + e] = ws[RECO + t];
    float xx = fminf(fmaxf(imputed, -8.f), 8.f);
    float f = (xx + 8.f) * 512.f;
    float fi = floorf(f);
    int i = (int)fi; i = i > 8191 ? 8191 : i;
    float w = f - fi;
    float t0 = ws[TAB + i], t1 = ws[TAB + i + 1];
    out[BS + e] = fmaf(w, t1 - t0, t0);
}

extern "C" void kernel_launch(void* const* d_in, const int* in_sizes, int n_in,
                              void* d_out, int out_size, void* d_ws, size_t ws_size,
                              hipStream_t stream)
{
    float* ws = (float*)d_ws;
    P29 a;
    for (int i = 0; i < 29; i++) a.p[i] = (const float*)d_in[i];
    const int* masks = (const int*)d_in[1];
    k_prep<<<34, 256, 0, stream>>>(a, ws);                    // block0 prep + 33 table blocks
    k_lstm<<<(2*BB*16)/256, 256, 0, stream>>>(a, masks, ws);  // 16 lanes per (b,dir)
    k_post<<<BS/256, 256, 0, stream>>>(a, masks, ws, (float*)d_out);
}